// Round 7
// baseline (642.549 us; speedup 1.0000x reference)
//
#include <hip/hip_runtime.h>
#include <hip/hip_bf16.h>
#include <hip/hip_cooperative_groups.h>

namespace cg = cooperative_groups;

#define N_TOK 4096
#define DIM   512
#define HID   1024
#define OUTD  512
#define NEXP  8
#define TOPK  2
#define GRID  512
#define HROWS 9216 // max padded rows

typedef __bf16 bf16;
typedef bf16  bf16x8 __attribute__((ext_vector_type(8)));
typedef bf16  bf16x4 __attribute__((ext_vector_type(4)));
typedef float f32x4  __attribute__((ext_vector_type(4)));

__device__ inline f32x4 mfma16(bf16x8 a, bf16x8 b, f32x4 c) {
    return __builtin_amdgcn_mfma_f32_16x16x32_bf16(a, b, c, 0, 0, 0);
}

__device__ inline void gload16(const bf16* g, char* l) {
    __builtin_amdgcn_global_load_lds(
        (const __attribute__((address_space(1))) void*)g,
        (__attribute__((address_space(3))) void*)l, 16, 0, 0);
}

// ---------- shared device helpers ----------

// 32x32 f32 tile transpose -> bf16 (LDS-staged, coalesced both sides)
__device__ inline void transpose32(const float* __restrict__ s, bf16* __restrict__ d,
                                   int C, int R, int c0, int r0, char* ldsb, int tid)
{
    float (*tile)[33] = (float(*)[33])ldsb;
    int tx = tid & 31, ty = tid >> 5;
#pragma unroll
    for (int i = 0; i < 4; ++i)
        tile[ty + i * 8][tx] = s[(size_t)(r0 + ty + i * 8) * C + c0 + tx];
    __syncthreads();
    int dc = tid >> 3, q = tid & 7;
    bf16x4 v;
#pragma unroll
    for (int j = 0; j < 4; ++j) v[j] = (bf16)tile[q * 4 + j][dc];
    *(bf16x4*)(d + (size_t)(c0 + dc) * R + r0 + q * 4) = v;
}

// gating for one token (one wave), WgT in LDS (wgs)
__device__ inline void gate_group(int n, const float* __restrict__ x,
    const float* __restrict__ wgs, const float* __restrict__ bg,
    bf16* __restrict__ xb, float* __restrict__ gates_out,
    float* __restrict__ topi_out, int* __restrict__ pick_e,
    float* __restrict__ pick_w, int l)
{
    const float4* x4 = (const float4*)(x + (size_t)n * DIM);
    float4 v0 = x4[l];
    float4 v1 = x4[l + 64];

    bf16x4 o0 = { (bf16)v0.x, (bf16)v0.y, (bf16)v0.z, (bf16)v0.w };
    bf16x4 o1 = { (bf16)v1.x, (bf16)v1.y, (bf16)v1.z, (bf16)v1.w };
    bf16x4* xb4 = (bf16x4*)(xb + (size_t)n * DIM);
    xb4[l]      = o0;
    xb4[l + 64] = o1;

    float acc[NEXP];
#pragma unroll
    for (int e = 0; e < NEXP; ++e) {
        const float4* wr = (const float4*)(wgs + e * DIM);
        float4 w0 = wr[l];
        float4 w1 = wr[l + 64];
        acc[e] = v0.x * w0.x + v0.y * w0.y + v0.z * w0.z + v0.w * w0.w
               + v1.x * w1.x + v1.y * w1.y + v1.z * w1.z + v1.w * w1.w;
    }
#pragma unroll
    for (int off = 32; off >= 1; off >>= 1) {
#pragma unroll
        for (int e = 0; e < NEXP; ++e) acc[e] += __shfl_xor(acc[e], off, 64);
    }
#pragma unroll
    for (int e = 0; e < NEXP; ++e) acc[e] += bg[e];

    float m = acc[0];
#pragma unroll
    for (int e = 1; e < NEXP; ++e) m = fmaxf(m, acc[e]);
    float g[NEXP];
    float s = 0.f;
#pragma unroll
    for (int e = 0; e < NEXP; ++e) { g[e] = expf(acc[e] - m); s += g[e]; }
    float inv_s = 1.f / s;
#pragma unroll
    for (int e = 0; e < NEXP; ++e) g[e] *= inv_s;

    if (l < NEXP) gates_out[n * NEXP + l] = g[l];

    if (l == 0) {
        int m1 = 0;
#pragma unroll
        for (int e = 1; e < NEXP; ++e) if (g[e] > g[m1]) m1 = e;
        int m2 = (m1 == 0) ? 1 : 0;
#pragma unroll
        for (int e = 0; e < NEXP; ++e) if (e != m1 && g[e] > g[m2]) m2 = e;
        float v1g = g[m1], v2g = g[m2];
        float inv = 1.f / (v1g + v2g);
        topi_out[n * TOPK + 0] = (float)m1;
        topi_out[n * TOPK + 1] = (float)m2;
        int2 pe = { m1, m2 };
        float2 pw = { v1g * inv, v2g * inv };
        *(int2*)(pick_e + n * 2) = pe;
        *(float2*)(pick_w + n * 2) = pw;
    }
}

// decode 128-row m-tile mt -> (expert, row base, list offset, count)
__device__ inline void find_tile(const int* cv, int mt, int& e, int& rb, int& i0, int& ce)
{
    int at = 0, base = 0;
    e = 0; rb = 0; i0 = 0; ce = 0;
#pragma unroll
    for (int ee = 0; ee < NEXP; ++ee) {
        int c = cv[ee]; int n1 = (c + 127) >> 7;
        if (mt >= at && mt < at + n1) {
            e = ee; int lt = mt - at; rb = base + lt * 128; i0 = lt * 128; ce = c;
        }
        at += n1; base += n1 << 7;
    }
}

__device__ inline int tiles_total(const int* cv)
{
    int t = 0;
#pragma unroll
    for (int ee = 0; ee < NEXP; ++ee) t += (cv[ee] + 127) >> 7;
    return t;
}

// l1 tile 128x128, K=512: h = relu(X_gather @ W1_e + b1)
__device__ inline void l1_tile(const bf16* __restrict__ xb, const bf16* __restrict__ w1e,
    const float* __restrict__ b1e, const int* __restrict__ tl,
    bf16* __restrict__ h, char* lds, int tid, int rb, int i0, int cnt, int n0)
{
    int w = tid >> 6, l = tid & 63;
    int c0 = w * 128 + l, c1 = c0 + 64;
    int rA0 = c0 >> 2, rA1 = c1 >> 2;
    int kA0 = (c0 & 3) ^ ((rA0 & 3) ^ ((rA0 >> 2) & 1));
    int kA1 = (c1 & 3) ^ ((rA1 & 3) ^ ((rA1 >> 2) & 1));
    int iA0 = i0 + rA0, iA1 = i0 + rA1;
    int tok0 = iA0 < cnt ? (tl[iA0] >> 1) : 0;
    int tok1 = iA1 < cnt ? (tl[iA1] >> 1) : 0;
    const bf16* sA0 = xb + (size_t)tok0 * DIM + kA0 * 8;
    const bf16* sA1 = xb + (size_t)tok1 * DIM + kA1 * 8;
    const bf16* sB0 = w1e + (size_t)(n0 + rA0) * DIM + kA0 * 8;
    const bf16* sB1 = w1e + (size_t)(n0 + rA1) * DIM + kA1 * 8;
    int oA0 = c0 * 16, oA1 = c1 * 16;

    f32x4 acc[4][4];
#pragma unroll
    for (int mf = 0; mf < 4; ++mf)
#pragma unroll
        for (int nf = 0; nf < 4; ++nf) acc[mf][nf] = (f32x4){0.f, 0.f, 0.f, 0.f};

    int wm = w >> 1, wn = w & 1;
    int lr = l & 15;
    int kb = ((l >> 4) ^ ((l & 3) ^ ((l >> 2) & 1))) * 16;

    {
        char* A = lds;       char* B = lds + 8192;
        gload16(sA0, A + oA0); gload16(sA1, A + oA1);
        gload16(sB0, B + oA0); gload16(sB1, B + oA1);
    }
    for (int ks = 0; ks < 16; ++ks) {
        __syncthreads();
        if (ks < 15) {
            char* A = lds + (((ks + 1) & 1) * 16384);
            char* B = A + 8192;
            int kof = (ks + 1) * 32;
            gload16(sA0 + kof, A + oA0); gload16(sA1 + kof, A + oA1);
            gload16(sB0 + kof, B + oA0); gload16(sB1 + kof, B + oA1);
        }
        char* A = lds + ((ks & 1) * 16384);
        char* B = A + 8192;
        bf16x8 af[4], bfr[4];
#pragma unroll
        for (int mf = 0; mf < 4; ++mf)
            af[mf] = *(const bf16x8*)(A + (wm * 64 + mf * 16 + lr) * 64 + kb);
#pragma unroll
        for (int nf = 0; nf < 4; ++nf)
            bfr[nf] = *(const bf16x8*)(B + (wn * 64 + nf * 16 + lr) * 64 + kb);
#pragma unroll
        for (int mf = 0; mf < 4; ++mf)
#pragma unroll
            for (int nf = 0; nf < 4; ++nf)
                acc[mf][nf] = mfma16(af[mf], bfr[nf], acc[mf][nf]);
    }

#pragma unroll
    for (int nf = 0; nf < 4; ++nf) {
        int colg = n0 + wn * 64 + nf * 16 + lr;
        float bias = b1e[colg];
#pragma unroll
        for (int mf = 0; mf < 4; ++mf) {
#pragma unroll
            for (int r = 0; r < 4; ++r) {
                int gr = rb + wm * 64 + mf * 16 + (l >> 4) * 4 + r;
                float v = fmaxf(acc[mf][nf][r] + bias, 0.f);
                h[(size_t)gr * HID + colg] = (bf16)v;
            }
        }
    }
}

// l2 tile 64x128, K=1024: ybuf[pick] = h @ W2_e
__device__ inline void l2_tile64(const bf16* __restrict__ h, const bf16* __restrict__ w2e,
    const int* __restrict__ tl, bf16* __restrict__ ybuf, char* lds, int tid,
    int rb, int i0, int cnt, int n0)
{
    int w = tid >> 6, l = tid & 63;
    int cA = tid; int rA = cA >> 2;
    int kA = (cA & 3) ^ ((rA & 3) ^ ((rA >> 2) & 1));
    const bf16* sA = h + (size_t)(rb + rA) * HID + kA * 8;
    int cB0 = w * 128 + l, cB1 = cB0 + 64;
    int rB0 = cB0 >> 2, rB1 = cB1 >> 2;
    int kB0 = (cB0 & 3) ^ ((rB0 & 3) ^ ((rB0 >> 2) & 1));
    int kB1 = (cB1 & 3) ^ ((rB1 & 3) ^ ((rB1 >> 2) & 1));
    const bf16* sB0 = w2e + (size_t)(n0 + rB0) * HID + kB0 * 8;
    const bf16* sB1 = w2e + (size_t)(n0 + rB1) * HID + kB1 * 8;
    int oA = cA * 16, oB0 = cB0 * 16, oB1 = cB1 * 16;

    f32x4 acc[2][4];
#pragma unroll
    for (int mf = 0; mf < 2; ++mf)
#pragma unroll
        for (int nf = 0; nf < 4; ++nf) acc[mf][nf] = (f32x4){0.f, 0.f, 0.f, 0.f};

    int wm = w >> 1, wn = w & 1;
    int lr = l & 15;
    int kb = ((l >> 4) ^ ((l & 3) ^ ((l >> 2) & 1))) * 16;

    {
        char* A = lds; char* B = lds + 4096;
        gload16(sA, A + oA); gload16(sB0, B + oB0); gload16(sB1, B + oB1);
    }
    for (int ks = 0; ks < 32; ++ks) {
        __syncthreads();
        if (ks < 31) {
            char* A = lds + (((ks + 1) & 1) * 12288);
            char* B = A + 4096;
            int kof = (ks + 1) * 32;
            gload16(sA + kof, A + oA);
            gload16(sB0 + kof, B + oB0); gload16(sB1 + kof, B + oB1);
        }
        char* A = lds + ((ks & 1) * 12288);
        char* B = A + 4096;
        bf16x8 af[2], bfr[4];
#pragma unroll
        for (int mf = 0; mf < 2; ++mf)
            af[mf] = *(const bf16x8*)(A + (wm * 32 + mf * 16 + lr) * 64 + kb);
#pragma unroll
        for (int nf = 0; nf < 4; ++nf)
            bfr[nf] = *(const bf16x8*)(B + (wn * 64 + nf * 16 + lr) * 64 + kb);
#pragma unroll
        for (int mf = 0; mf < 2; ++mf)
#pragma unroll
            for (int nf = 0; nf < 4; ++nf)
                acc[mf][nf] = mfma16(af[mf], bfr[nf], acc[mf][nf]);
    }

#pragma unroll
    for (int mf = 0; mf < 2; ++mf) {
#pragma unroll
        for (int r = 0; r < 4; ++r) {
            int rloc = wm * 32 + mf * 16 + (l >> 4) * 4 + r;
            int i = i0 + rloc;
            if (i < cnt) {
                int pi = tl[i];
                bf16* yrow = ybuf + (size_t)pi * OUTD;
#pragma unroll
                for (int nf = 0; nf < 4; ++nf)
                    yrow[n0 + wn * 64 + nf * 16 + lr] = (bf16)acc[mf][nf][r];
            }
        }
    }
}

// combine one token (one wave)
__device__ inline void combine_token(int n, const bf16* __restrict__ ybuf,
    const float* __restrict__ b2, const int* __restrict__ pick_e,
    const float* __restrict__ pick_w, float* __restrict__ out, int l)
{
    int e0 = pick_e[n * 2], e1 = pick_e[n * 2 + 1];
    float w0 = pick_w[n * 2], w1 = pick_w[n * 2 + 1];
    const bf16x8* y0 = (const bf16x8*)(ybuf + (size_t)(n * 2) * OUTD);
    const bf16x8* y1 = (const bf16x8*)(ybuf + (size_t)(n * 2 + 1) * OUTD);
    const float4* b20 = (const float4*)(b2 + e0 * OUTD);
    const float4* b21 = (const float4*)(b2 + e1 * OUTD);
    float4* o4 = (float4*)(out + (size_t)n * OUTD);

    bf16x8 a = y0[l];
    bf16x8 b = y1[l];
    float4 c0 = b20[l * 2], c1 = b20[l * 2 + 1];
    float4 d0 = b21[l * 2], d1 = b21[l * 2 + 1];
    float4 r0, r1;
    r0.x = w0 * ((float)a[0] + c0.x) + w1 * ((float)b[0] + d0.x);
    r0.y = w0 * ((float)a[1] + c0.y) + w1 * ((float)b[1] + d0.y);
    r0.z = w0 * ((float)a[2] + c0.z) + w1 * ((float)b[2] + d0.z);
    r0.w = w0 * ((float)a[3] + c0.w) + w1 * ((float)b[3] + d0.w);
    r1.x = w0 * ((float)a[4] + c1.x) + w1 * ((float)b[4] + d1.x);
    r1.y = w0 * ((float)a[5] + c1.y) + w1 * ((float)b[5] + d1.y);
    r1.z = w0 * ((float)a[6] + c1.z) + w1 * ((float)b[6] + d1.z);
    r1.w = w0 * ((float)a[7] + c1.w) + w1 * ((float)b[7] + d1.w);
    o4[l * 2]     = r0;
    o4[l * 2 + 1] = r1;
}

// ---------------- mega: everything in one cooperative launch ----------------
__global__ __launch_bounds__(256, 2) void moe_mega(
    const float* __restrict__ x, const float* __restrict__ W1,
    const float* __restrict__ b1, const float* __restrict__ W2,
    const float* __restrict__ b2, const float* __restrict__ Wg,
    const float* __restrict__ bg,
    bf16* __restrict__ W1t, bf16* __restrict__ W2t, bf16* __restrict__ xb,
    bf16* __restrict__ hbuf, bf16* __restrict__ ybuf,
    int* __restrict__ counts, int* __restrict__ tlist,
    int* __restrict__ pick_e, float* __restrict__ pick_w,
    float* __restrict__ out, float* __restrict__ gates_out,
    float* __restrict__ topi_out)
{
    cg::grid_group grid = cg::this_grid();
    __shared__ __align__(16) char lds[32768];
    __shared__ int cnt_s;

    const int bid = blockIdx.x, tid = threadIdx.x;
    const int w = tid >> 6, l = tid & 63;

    // ---- P1: W1 transpose (4096 tasks) + gate (1024 tasks) ----
    for (int t = bid; t < 5120; t += GRID) {
        __syncthreads();
        if (t < 4096) {
            int e = t >> 9, rem = t & 511;
            transpose32(W1 + (size_t)e * DIM * HID, W1t + (size_t)e * DIM * HID,
                        HID, DIM, (rem & 31) * 32, (rem >> 5) * 32, lds, tid);
        } else {
            float* wgs = (float*)lds;
            const float4* Wg4 = (const float4*)Wg;
            for (int i = tid; i < DIM * NEXP / 4; i += 256) {
                float4 v = Wg4[i];
#pragma unroll
                for (int j = 0; j < 4; ++j) {
                    int idx = i * 4 + j;
                    wgs[(idx & 7) * DIM + (idx >> 3)] = ((const float*)&v)[j];
                }
            }
            __syncthreads();
            gate_group((t - 4096) * 4 + w, x, wgs, bg, xb, gates_out, topi_out,
                       pick_e, pick_w, l);
        }
    }
    __threadfence(); grid.sync(); __threadfence();

    // ---- P2: bucket (blocks 0-7) overlapped with W2 transpose (blocks 8+) ----
    if (bid < NEXP) {
        if (tid == 0) cnt_s = 0;
        __syncthreads();
        int e = bid;
        for (int i = tid; i < N_TOK * 2; i += 256) {
            if (pick_e[i] == e) {
                int p = atomicAdd(&cnt_s, 1);
                tlist[e * N_TOK + p] = i;
            }
        }
        __syncthreads();
        if (tid == 0) counts[e] = cnt_s;
    } else {
        for (int t = bid - 8; t < 4096; t += GRID - 8) {
            __syncthreads();
            int e = t >> 9, rem = t & 511;
            transpose32(W2 + (size_t)e * HID * OUTD, W2t + (size_t)e * HID * OUTD,
                        OUTD, HID, (rem & 15) * 32, (rem >> 4) * 32, lds, tid);
        }
    }
    __threadfence(); grid.sync(); __threadfence();

    int cv[NEXP];
#pragma unroll
    for (int e = 0; e < NEXP; ++e) cv[e] = counts[e];
    int T1 = tiles_total(cv);

    // ---- P3: layer1, 128x128 tiles ----
    for (int t = bid; t < T1 * 8; t += GRID) {
        __syncthreads();
        int mt = t >> 3, nt = t & 7;
        int e, rb, i0, ce;
        find_tile(cv, mt, e, rb, i0, ce);
        l1_tile(xb, W1t + (size_t)e * HID * DIM, b1 + e * HID,
                tlist + e * N_TOK, hbuf, lds, tid, rb, i0, ce, nt * 128);
    }
    __threadfence(); grid.sync(); __threadfence();

    // ---- P4: layer2, 64x128 half-tiles ----
    for (int t = bid; t < T1 * 8; t += GRID) {
        __syncthreads();
        int mth = t >> 2, nt = t & 3;
        int mt = mth >> 1, half = mth & 1;
        int e, rb, i0, ce;
        find_tile(cv, mt, e, rb, i0, ce);
        l2_tile64(hbuf, W2t + (size_t)e * OUTD * HID, tlist + e * N_TOK,
                  ybuf, lds, tid, rb + half * 64, i0 + half * 64, ce, nt * 128);
    }
    __threadfence(); grid.sync(); __threadfence();

    // ---- P5: combine, 8 tokens per block ----
#pragma unroll
    for (int j = 0; j < 2; ++j)
        combine_token(bid * 8 + w * 2 + j, ybuf, b2, pick_e, pick_w, out, l);
}

// ---------------- fallback path (non-cooperative) ----------------
__global__ __launch_bounds__(256) void fb_prep_gate(
    const float* __restrict__ W1, const float* __restrict__ W2,
    const float* __restrict__ Wg, const float* __restrict__ bg,
    const float* __restrict__ x,
    bf16* __restrict__ W1t, bf16* __restrict__ W2t, bf16* __restrict__ xb,
    float* __restrict__ gates_out, float* __restrict__ topi_out,
    int* __restrict__ pick_e, float* __restrict__ pick_w)
{
    __shared__ __align__(16) char lds[16896];
    int b = blockIdx.x, tid = threadIdx.x;
    if (b >= 8192) {
        float* wgs = (float*)lds;
        const float4* Wg4 = (const float4*)Wg;
        for (int i = tid; i < DIM * NEXP / 4; i += 256) {
            float4 v = Wg4[i];
#pragma unroll
            for (int j = 0; j < 4; ++j) {
                int idx = i * 4 + j;
                wgs[(idx & 7) * DIM + (idx >> 3)] = ((const float*)&v)[j];
            }
        }
        __syncthreads();
        gate_group((b - 8192) * 4 + (tid >> 6), x, wgs, bg, xb, gates_out,
                   topi_out, pick_e, pick_w, tid & 63);
        return;
    }
    if (b < 4096) {
        int e = b >> 9, rem = b & 511;
        transpose32(W1 + (size_t)e * DIM * HID, W1t + (size_t)e * DIM * HID,
                    HID, DIM, (rem & 31) * 32, (rem >> 5) * 32, lds, tid);
    } else {
        b -= 4096;
        int e = b >> 9, rem = b & 511;
        transpose32(W2 + (size_t)e * HID * OUTD, W2t + (size_t)e * HID * OUTD,
                    OUTD, HID, (rem & 15) * 32, (rem >> 4) * 32, lds, tid);
    }
}

__global__ __launch_bounds__(256) void fb_bucket(
    const int* __restrict__ pick_e, int* __restrict__ counts, int* __restrict__ tlist)
{
    __shared__ int cnt;
    if (threadIdx.x == 0) cnt = 0;
    __syncthreads();
    int e = blockIdx.x;
    for (int i = threadIdx.x; i < N_TOK * 2; i += 256) {
        if (pick_e[i] == e) {
            int p = atomicAdd(&cnt, 1);
            tlist[e * N_TOK + p] = i;
        }
    }
    __syncthreads();
    if (threadIdx.x == 0) counts[e] = cnt;
}

__global__ __launch_bounds__(256, 4) void fb_l1(
    const bf16* __restrict__ xb, const bf16* __restrict__ W1t,
    const float* __restrict__ b1, const int* __restrict__ counts,
    const int* __restrict__ tlist, bf16* __restrict__ hbuf)
{
    __shared__ __align__(16) char lds[32768];
    int cv[NEXP];
#pragma unroll
    for (int e = 0; e < NEXP; ++e) cv[e] = counts[e];
    int t = blockIdx.x;
    if (t >= tiles_total(cv) * 8) return;
    int mt = t >> 3, nt = t & 7;
    int e, rb, i0, ce;
    find_tile(cv, mt, e, rb, i0, ce);
    l1_tile(xb, W1t + (size_t)e * HID * DIM, b1 + e * HID,
            tlist + e * N_TOK, hbuf, lds, threadIdx.x, rb, i0, ce, nt * 128);
}

__global__ __launch_bounds__(256, 4) void fb_l2(
    const bf16* __restrict__ hbuf, const bf16* __restrict__ W2t,
    const int* __restrict__ counts, const int* __restrict__ tlist,
    bf16* __restrict__ ybuf)
{
    __shared__ __align__(16) char lds[24576];
    int cv[NEXP];
#pragma unroll
    for (int e = 0; e < NEXP; ++e) cv[e] = counts[e];
    int t = blockIdx.x;
    if (t >= tiles_total(cv) * 8) return;
    int mth = t >> 2, nt = t & 3;
    int mt = mth >> 1, half = mth & 1;
    int e, rb, i0, ce;
    find_tile(cv, mt, e, rb, i0, ce);
    l2_tile64(hbuf, W2t + (size_t)e * OUTD * HID, tlist + e * N_TOK,
              ybuf, lds, threadIdx.x, rb + half * 64, i0 + half * 64, ce, nt * 128);
}

__global__ __launch_bounds__(256) void fb_combine(
    const bf16* __restrict__ ybuf, const float* __restrict__ b2,
    const int* __restrict__ pick_e, const float* __restrict__ pick_w,
    float* __restrict__ out)
{
    int w = threadIdx.x >> 6, l = threadIdx.x & 63;
#pragma unroll
    for (int j = 0; j < 2; ++j)
        combine_token(blockIdx.x * 8 + w * 2 + j, ybuf, b2, pick_e, pick_w, out, l);
}

extern "C" void kernel_launch(void* const* d_in, const int* in_sizes, int n_in,
                              void* d_out, int out_size, void* d_ws, size_t ws_size,
                              hipStream_t stream)
{
    const float* x  = (const float*)d_in[0];
    const float* W1 = (const float*)d_in[1];
    const float* b1 = (const float*)d_in[2];
    const float* W2 = (const float*)d_in[3];
    const float* b2 = (const float*)d_in[4];
    const float* Wg = (const float*)d_in[5];
    const float* bg = (const float*)d_in[6];

    float* out_f   = (float*)d_out;
    float* gates_o = out_f + (size_t)N_TOK * OUTD;
    float* topi_o  = gates_o + (size_t)N_TOK * NEXP;

    char* ws = (char*)d_ws;
    size_t offW1t = 0;                                            // 8 MB
    size_t offW2t = offW1t + (size_t)NEXP * HID * DIM * 2;        // 8 MB
    size_t offXb  = offW2t + (size_t)NEXP * OUTD * HID * 2;       // 4 MB
    size_t offH   = offXb + (size_t)N_TOK * DIM * 2;              // 18.9 MB
    size_t offYb  = offH + (size_t)HROWS * HID * 2;               // 8 MB
    size_t offCnt = offYb + (size_t)N_TOK * 2 * OUTD * 2;
    size_t offTl  = offCnt + 256;
    size_t offPkE = offTl + (size_t)NEXP * N_TOK * 4;
    size_t offPkW = offPkE + (size_t)N_TOK * 2 * 4;

    bf16*  W1t    = (bf16*)(ws + offW1t);
    bf16*  W2t    = (bf16*)(ws + offW2t);
    bf16*  xbuf   = (bf16*)(ws + offXb);
    bf16*  hbuf   = (bf16*)(ws + offH);
    bf16*  ybuf   = (bf16*)(ws + offYb);
    int*   cnts   = (int*)(ws + offCnt);
    int*   tlist  = (int*)(ws + offTl);
    int*   pick_e = (int*)(ws + offPkE);
    float* pick_w = (float*)(ws + offPkW);

    void* args[] = {
        (void*)&x, (void*)&W1, (void*)&b1, (void*)&W2, (void*)&b2,
        (void*)&Wg, (void*)&bg,
        (void*)&W1t, (void*)&W2t, (void*)&xbuf, (void*)&hbuf, (void*)&ybuf,
        (void*)&cnts, (void*)&tlist, (void*)&pick_e, (void*)&pick_w,
        (void*)&out_f, (void*)&gates_o, (void*)&topi_o
    };
    hipError_t err = hipLaunchCooperativeKernel(
        (const void*)moe_mega, dim3(GRID), dim3(256), args, 0, stream);

    if (err != hipSuccess) {
        // fallback: same helpers, separate launches
        fb_prep_gate<<<8192 + N_TOK / 4, 256, 0, stream>>>(
            W1, W2, Wg, bg, x, W1t, W2t, xbuf, gates_o, topi_o, pick_e, pick_w);
        fb_bucket<<<NEXP, 256, 0, stream>>>(pick_e, cnts, tlist);
        fb_l1<<<576, 256, 0, stream>>>(xbuf, W1t, b1, cnts, tlist, hbuf);
        fb_l2<<<576, 256, 0, stream>>>(hbuf, W2t, cnts, tlist, ybuf);
        fb_combine<<<GRID, 256, 0, stream>>>(ybuf, b2, pick_e, pick_w, out_f);
    }
}

// Round 8
// 84.395 us; speedup vs baseline: 7.6136x; 7.6136x over previous
//
#include <hip/hip_runtime.h>
#include <hip/hip_bf16.h>

#define N_TOK 4096
#define DIM   512
#define HID   1024
#define OUTD  512
#define NEXP  8
#define TOPK  2

#define MT1 72     // max 128-row M-tiles
#define HROWS 9216 // max padded rows

typedef __bf16 bf16;
typedef bf16  bf16x8 __attribute__((ext_vector_type(8)));
typedef bf16  bf16x4 __attribute__((ext_vector_type(4)));
typedef float f32x4  __attribute__((ext_vector_type(4)));

__device__ inline f32x4 mfma16(bf16x8 a, bf16x8 b, f32x4 c) {
    return __builtin_amdgcn_mfma_f32_16x16x32_bf16(a, b, c, 0, 0, 0);
}

__device__ inline void gload16(const bf16* g, char* l) {
    __builtin_amdgcn_global_load_lds(
        (const __attribute__((address_space(1))) void*)g,
        (__attribute__((address_space(3))) void*)l, 16, 0, 0);
}

// decode 128-row m-tile mt -> (expert, row base, list offset, count)
__device__ inline void find_tile(const int* cv, int mt, int& e, int& rb, int& i0, int& ce)
{
    int at = 0, base = 0;
    e = 0; rb = 0; i0 = 0; ce = 0;
#pragma unroll
    for (int ee = 0; ee < NEXP; ++ee) {
        int c = cv[ee]; int n1 = (c + 127) >> 7;
        if (mt >= at && mt < at + n1) {
            e = ee; int lt = mt - at; rb = base + lt * 128; i0 = lt * 128; ce = c;
        }
        at += n1; base += n1 << 7;
    }
}

__device__ inline int tiles_total(const int* cv)
{
    int t = 0;
#pragma unroll
    for (int ee = 0; ee < NEXP; ++ee) t += (cv[ee] + 127) >> 7;
    return t;
}

// ------------- prep (W1/W2 transpose->bf16) + gate, one launch -------------
// blocks [0,4096): W1 [512][1024] -> W1t [1024][512]
// blocks [4096,8192): W2 [1024][512] -> W2t [512][1024]
// blocks [8192,9216): gating (4 tokens per block); WgT built in LDS
__global__ __launch_bounds__(256) void prep_gate_kernel(
    const float* __restrict__ W1, const float* __restrict__ W2,
    const float* __restrict__ Wg, const float* __restrict__ bg,
    const float* __restrict__ x,
    bf16* __restrict__ W1t, bf16* __restrict__ W2t,
    bf16* __restrict__ xb,
    float* __restrict__ gates_out, float* __restrict__ topi_out,
    int* __restrict__ pick_e, float* __restrict__ pick_w)
{
    __shared__ __align__(16) float smem[NEXP * DIM];   // 16 KB (gate) / tile (prep)
    int b = blockIdx.x;

    if (b >= 8192) {
        // ---------------- gate path ----------------
        const float4* Wg4 = (const float4*)Wg;
        for (int i = threadIdx.x; i < DIM * NEXP / 4; i += 256) {
            float4 v = Wg4[i];
#pragma unroll
            for (int j = 0; j < 4; ++j) {
                int idx = i * 4 + j;
                smem[(idx & 7) * DIM + (idx >> 3)] = ((const float*)&v)[j];
            }
        }
        __syncthreads();

        int wave = threadIdx.x >> 6;
        int lane = threadIdx.x & 63;
        int n = (b - 8192) * 4 + wave;

        const float4* x4 = (const float4*)(x + (size_t)n * DIM);
        float4 v0 = x4[lane];
        float4 v1 = x4[lane + 64];

        bf16x4 o0 = { (bf16)v0.x, (bf16)v0.y, (bf16)v0.z, (bf16)v0.w };
        bf16x4 o1 = { (bf16)v1.x, (bf16)v1.y, (bf16)v1.z, (bf16)v1.w };
        bf16x4* xb4 = (bf16x4*)(xb + (size_t)n * DIM);
        xb4[lane]      = o0;
        xb4[lane + 64] = o1;

        float acc[NEXP];
#pragma unroll
        for (int e = 0; e < NEXP; ++e) {
            const float4* wr = (const float4*)(smem + e * DIM);
            float4 w0 = wr[lane];
            float4 w1 = wr[lane + 64];
            acc[e] = v0.x * w0.x + v0.y * w0.y + v0.z * w0.z + v0.w * w0.w
                   + v1.x * w1.x + v1.y * w1.y + v1.z * w1.z + v1.w * w1.w;
        }
#pragma unroll
        for (int off = 32; off >= 1; off >>= 1) {
#pragma unroll
            for (int e = 0; e < NEXP; ++e) acc[e] += __shfl_xor(acc[e], off, 64);
        }
#pragma unroll
        for (int e = 0; e < NEXP; ++e) acc[e] += bg[e];

        float m = acc[0];
#pragma unroll
        for (int e = 1; e < NEXP; ++e) m = fmaxf(m, acc[e]);
        float g[NEXP];
        float s = 0.f;
#pragma unroll
        for (int e = 0; e < NEXP; ++e) { g[e] = expf(acc[e] - m); s += g[e]; }
        float inv_s = 1.f / s;
#pragma unroll
        for (int e = 0; e < NEXP; ++e) g[e] *= inv_s;

        if (lane < NEXP) gates_out[n * NEXP + lane] = g[lane];

        if (lane == 0) {
            int m1 = 0;
#pragma unroll
            for (int e = 1; e < NEXP; ++e) if (g[e] > g[m1]) m1 = e;
            int m2 = (m1 == 0) ? 1 : 0;
#pragma unroll
            for (int e = 0; e < NEXP; ++e) if (e != m1 && g[e] > g[m2]) m2 = e;
            float v1g = g[m1], v2g = g[m2];
            float inv = 1.f / (v1g + v2g);
            topi_out[n * TOPK + 0] = (float)m1;
            topi_out[n * TOPK + 1] = (float)m2;
            int2 pe = { m1, m2 };
            float2 pw = { v1g * inv, v2g * inv };
            *(int2*)(pick_e + n * 2) = pe;
            *(float2*)(pick_w + n * 2) = pw;
        }
        return;
    }

    // ---------------- transpose path ----------------
    float (*tile)[33] = (float(*)[33])smem;   // [32][33]
    const float* src; bf16* dst; int R, C, tilex, rem, e;
    if (b < 4096) {
        e = b >> 9; rem = b & 511; R = DIM; C = HID; tilex = 32;
        src = W1; dst = W1t;
    } else {
        b -= 4096;
        e = b >> 9; rem = b & 511; R = HID; C = OUTD; tilex = 16;
        src = W2; dst = W2t;
    }
    const float* s = src + (size_t)e * R * C;
    bf16* d = dst + (size_t)e * R * C;
    int c0 = (rem % tilex) * 32, r0 = (rem / tilex) * 32;

    int tx = threadIdx.x & 31, ty = threadIdx.x >> 5;
#pragma unroll
    for (int i = 0; i < 4; ++i) {
        int r = ty + i * 8;
        tile[r][tx] = s[(size_t)(r0 + r) * C + c0 + tx];
    }
    __syncthreads();

    int t = threadIdx.x;
    int dc = t >> 3, q = t & 7;
    bf16x4 v;
#pragma unroll
    for (int j = 0; j < 4; ++j) v[j] = (bf16)tile[q * 4 + j][dc];
    *(bf16x4*)(d + (size_t)(c0 + dc) * R + r0 + q * 4) = v;
}

// ------------- bucket: 8 blocks (one per expert); stores pick-index -------------
__global__ __launch_bounds__(256) void bucket_kernel(
    const int* __restrict__ pick_e,
    int* __restrict__ counts, int* __restrict__ tlist)
{
    __shared__ int cnt;
    if (threadIdx.x == 0) cnt = 0;
    __syncthreads();
    int e = blockIdx.x;
    for (int i = threadIdx.x; i < N_TOK * 2; i += 256) {
        if (pick_e[i] == e) {
            int p = atomicAdd(&cnt, 1);
            tlist[e * N_TOK + p] = i;   // pick index: token*2 + slot
        }
    }
    __syncthreads();
    if (threadIdx.x == 0) counts[e] = cnt;
}

// Swizzled K-inner LDS layout (rule #21): slot(row,kc) = row*4 + (kc ^ h(row)),
// h(row) = (row&3) ^ ((row>>2)&1); LDS dest linear, global source inverse-swizzled,
// ds_read applies same XOR -> 2-way bank aliasing (free).

// ------------- layer1: h = relu(X_gather @ W1_e + b1), tile 128x128, K=512 -------------
__global__ __launch_bounds__(256, 4) void l1_kernel(
    const bf16* __restrict__ xb, const bf16* __restrict__ W1t,
    const float* __restrict__ b1, const int* __restrict__ counts,
    const int* __restrict__ tlist, bf16* __restrict__ h)
{
    int cv[NEXP];
#pragma unroll
    for (int e = 0; e < NEXP; ++e) cv[e] = counts[e];
    if (blockIdx.x >= tiles_total(cv) * 8) return;
    int mt = blockIdx.x >> 3, nt = blockIdx.x & 7;
    int e, rb, i0, cnt;
    find_tile(cv, mt, e, rb, i0, cnt);

    __shared__ __align__(16) char lds[32768];  // 2 bufs x (A 8KB + B 8KB)

    int tid = threadIdx.x, w = tid >> 6, l = tid & 63;
    int c0 = w * 128 + l, c1 = c0 + 64;
    int rA0 = c0 >> 2, rA1 = c1 >> 2;
    int kA0 = (c0 & 3) ^ ((rA0 & 3) ^ ((rA0 >> 2) & 1));
    int kA1 = (c1 & 3) ^ ((rA1 & 3) ^ ((rA1 >> 2) & 1));
    int iA0 = i0 + rA0, iA1 = i0 + rA1;
    const int* tl = tlist + e * N_TOK;
    int tok0 = iA0 < cnt ? (tl[iA0] >> 1) : 0;
    int tok1 = iA1 < cnt ? (tl[iA1] >> 1) : 0;
    const bf16* sA0 = xb + (size_t)tok0 * DIM + kA0 * 8;
    const bf16* sA1 = xb + (size_t)tok1 * DIM + kA1 * 8;
    int n0 = nt * 128;
    const bf16* w1e = W1t + (size_t)e * HID * DIM;
    const bf16* sB0 = w1e + (size_t)(n0 + rA0) * DIM + kA0 * 8;
    const bf16* sB1 = w1e + (size_t)(n0 + rA1) * DIM + kA1 * 8;
    int oA0 = c0 * 16, oA1 = c1 * 16;

    f32x4 acc[4][4];
#pragma unroll
    for (int mf = 0; mf < 4; ++mf)
#pragma unroll
        for (int nf = 0; nf < 4; ++nf) acc[mf][nf] = (f32x4){0.f, 0.f, 0.f, 0.f};

    int wm = w >> 1, wn = w & 1;
    int lr = l & 15;
    int kb = ((l >> 4) ^ ((l & 3) ^ ((l >> 2) & 1))) * 16;

    {
        char* A = lds;       char* B = lds + 8192;
        gload16(sA0, A + oA0); gload16(sA1, A + oA1);
        gload16(sB0, B + oA0); gload16(sB1, B + oA1);
    }

    for (int ks = 0; ks < 16; ++ks) {
        __syncthreads();
        if (ks < 15) {
            char* A = lds + (((ks + 1) & 1) * 16384);
            char* B = A + 8192;
            int kof = (ks + 1) * 32;
            gload16(sA0 + kof, A + oA0); gload16(sA1 + kof, A + oA1);
            gload16(sB0 + kof, B + oA0); gload16(sB1 + kof, B + oA1);
        }
        char* A = lds + ((ks & 1) * 16384);
        char* B = A + 8192;
        bf16x8 af[4], bfr[4];
#pragma unroll
        for (int mf = 0; mf < 4; ++mf)
            af[mf] = *(const bf16x8*)(A + (wm * 64 + mf * 16 + lr) * 64 + kb);
#pragma unroll
        for (int nf = 0; nf < 4; ++nf)
            bfr[nf] = *(const bf16x8*)(B + (wn * 64 + nf * 16 + lr) * 64 + kb);
#pragma unroll
        for (int mf = 0; mf < 4; ++mf)
#pragma unroll
            for (int nf = 0; nf < 4; ++nf)
                acc[mf][nf] = mfma16(af[mf], bfr[nf], acc[mf][nf]);
    }

    const float* b1e = b1 + e * HID;
#pragma unroll
    for (int nf = 0; nf < 4; ++nf) {
        int colg = n0 + wn * 64 + nf * 16 + lr;
        float bias = b1e[colg];
#pragma unroll
        for (int mf = 0; mf < 4; ++mf) {
#pragma unroll
            for (int r = 0; r < 4; ++r) {
                int gr = rb + wm * 64 + mf * 16 + (l >> 4) * 4 + r;
                float v = fmaxf(acc[mf][nf][r] + bias, 0.f);
                h[(size_t)gr * HID + colg] = (bf16)v;
            }
        }
    }
}

// ------------- layer2: ybuf[pick] = h @ W2_e, tile 64x128, K=1024 -------------
__global__ __launch_bounds__(256, 4) void l2_kernel(
    const bf16* __restrict__ h, const bf16* __restrict__ W2t,
    const int* __restrict__ counts, const int* __restrict__ tlist,
    bf16* __restrict__ ybuf)
{
    int cv[NEXP];
#pragma unroll
    for (int e = 0; e < NEXP; ++e) cv[e] = counts[e];
    if (blockIdx.x >= tiles_total(cv) * 8) return;
    int mth = blockIdx.x >> 2, nt = blockIdx.x & 3;
    int mt = mth >> 1, half = mth & 1;
    int e, rb, i0, cnt;
    find_tile(cv, mt, e, rb, i0, cnt);
    rb += half * 64; i0 += half * 64;

    __shared__ __align__(16) char lds[24576];  // 2 bufs x (A 4KB + B 8KB)

    int tid = threadIdx.x, w = tid >> 6, l = tid & 63;
    int cA = tid; int rA = cA >> 2;
    int kA = (cA & 3) ^ ((rA & 3) ^ ((rA >> 2) & 1));
    const bf16* sA = h + (size_t)(rb + rA) * HID + kA * 8;
    int cB0 = w * 128 + l, cB1 = cB0 + 64;
    int rB0 = cB0 >> 2, rB1 = cB1 >> 2;
    int kB0 = (cB0 & 3) ^ ((rB0 & 3) ^ ((rB0 >> 2) & 1));
    int kB1 = (cB1 & 3) ^ ((rB1 & 3) ^ ((rB1 >> 2) & 1));
    int n0 = nt * 128;
    const bf16* w2e = W2t + (size_t)e * OUTD * HID;
    const bf16* sB0 = w2e + (size_t)(n0 + rB0) * HID + kB0 * 8;
    const bf16* sB1 = w2e + (size_t)(n0 + rB1) * HID + kB1 * 8;
    int oA = cA * 16, oB0 = cB0 * 16, oB1 = cB1 * 16;

    f32x4 acc[2][4];
#pragma unroll
    for (int mf = 0; mf < 2; ++mf)
#pragma unroll
        for (int nf = 0; nf < 4; ++nf) acc[mf][nf] = (f32x4){0.f, 0.f, 0.f, 0.f};

    int wm = w >> 1, wn = w & 1;
    int lr = l & 15;
    int kb = ((l >> 4) ^ ((l & 3) ^ ((l >> 2) & 1))) * 16;

    {
        char* A = lds; char* B = lds + 4096;
        gload16(sA, A + oA); gload16(sB0, B + oB0); gload16(sB1, B + oB1);
    }

    for (int ks = 0; ks < 32; ++ks) {
        __syncthreads();
        if (ks < 31) {
            char* A = lds + (((ks + 1) & 1) * 12288);
            char* B = A + 4096;
            int kof = (ks + 1) * 32;
            gload16(sA + kof, A + oA);
            gload16(sB0 + kof, B + oB0); gload16(sB1 + kof, B + oB1);
        }
        char* A = lds + ((ks & 1) * 12288);
        char* B = A + 4096;
        bf16x8 af[2], bfr[4];
#pragma unroll
        for (int mf = 0; mf < 2; ++mf)
            af[mf] = *(const bf16x8*)(A + (wm * 32 + mf * 16 + lr) * 64 + kb);
#pragma unroll
        for (int nf = 0; nf < 4; ++nf)
            bfr[nf] = *(const bf16x8*)(B + (wn * 64 + nf * 16 + lr) * 64 + kb);
#pragma unroll
        for (int mf = 0; mf < 2; ++mf)
#pragma unroll
            for (int nf = 0; nf < 4; ++nf)
                acc[mf][nf] = mfma16(af[mf], bfr[nf], acc[mf][nf]);
    }

    const int* tl = tlist + e * N_TOK;
#pragma unroll
    for (int mf = 0; mf < 2; ++mf) {
#pragma unroll
        for (int r = 0; r < 4; ++r) {
            int rloc = wm * 32 + mf * 16 + (l >> 4) * 4 + r;
            int i = i0 + rloc;
            if (i < cnt) {
                int pi = tl[i];
                bf16* yrow = ybuf + (size_t)pi * OUTD;
#pragma unroll
                for (int nf = 0; nf < 4; ++nf)
                    yrow[n0 + wn * 64 + nf * 16 + lr] = (bf16)acc[mf][nf][r];
            }
        }
    }
}

// ------------- combine: out[n] = w0*(y0+b2[e0]) + w1*(y1+b2[e1]) -------------
__global__ __launch_bounds__(256) void combine_kernel(
    const bf16* __restrict__ ybuf, const float* __restrict__ b2,
    const int* __restrict__ pick_e, const float* __restrict__ pick_w,
    float* __restrict__ out)
{
    int w = threadIdx.x >> 6;
    int l = threadIdx.x & 63;
#pragma unroll
    for (int j = 0; j < 2; ++j) {
        int n = blockIdx.x * 8 + w * 2 + j;
        int e0 = pick_e[n * 2], e1 = pick_e[n * 2 + 1];
        float w0 = pick_w[n * 2], w1 = pick_w[n * 2 + 1];

        const bf16x8* y0 = (const bf16x8*)(ybuf + (size_t)(n * 2) * OUTD);
        const bf16x8* y1 = (const bf16x8*)(ybuf + (size_t)(n * 2 + 1) * OUTD);
        const float4* b20 = (const float4*)(b2 + e0 * OUTD);
        const float4* b21 = (const float4*)(b2 + e1 * OUTD);
        float4* o4 = (float4*)(out + (size_t)n * OUTD);

        bf16x8 a = y0[l];
        bf16x8 b = y1[l];
        float4 c0 = b20[l * 2], c1 = b20[l * 2 + 1];
        float4 d0 = b21[l * 2], d1 = b21[l * 2 + 1];

        float4 r0, r1;
        r0.x = w0 * ((float)a[0] + c0.x) + w1 * ((float)b[0] + d0.x);
        r0.y = w0 * ((float)a[1] + c0.y) + w1 * ((float)b[1] + d0.y);
        r0.z = w0 * ((float)a[2] + c0.z) + w1 * ((float)b[2] + d0.z);
        r0.w = w0 * ((float)a[3] + c0.w) + w1 * ((float)b[3] + d0.w);
        r1.x = w0 * ((float)a[4] + c1.x) + w1 * ((float)b[4] + d1.x);
        r1.y = w0 * ((float)a[5] + c1.y) + w1 * ((float)b[5] + d1.y);
        r1.z = w0 * ((float)a[6] + c1.z) + w1 * ((float)b[6] + d1.z);
        r1.w = w0 * ((float)a[7] + c1.w) + w1 * ((float)b[7] + d1.w);
        o4[l * 2]     = r0;
        o4[l * 2 + 1] = r1;
    }
}

extern "C" void kernel_launch(void* const* d_in, const int* in_sizes, int n_in,
                              void* d_out, int out_size, void* d_ws, size_t ws_size,
                              hipStream_t stream)
{
    const float* x  = (const float*)d_in[0];
    const float* W1 = (const float*)d_in[1];
    const float* b1 = (const float*)d_in[2];
    const float* W2 = (const float*)d_in[3];
    const float* b2 = (const float*)d_in[4];
    const float* Wg = (const float*)d_in[5];
    const float* bg = (const float*)d_in[6];

    float* out_f   = (float*)d_out;
    float* gates_o = out_f + (size_t)N_TOK * OUTD;
    float* topi_o  = gates_o + (size_t)N_TOK * NEXP;

    char* ws = (char*)d_ws;
    size_t offW1t = 0;                                            // 8 MB
    size_t offW2t = offW1t + (size_t)NEXP * HID * DIM * 2;        // 8 MB
    size_t offXb  = offW2t + (size_t)NEXP * OUTD * HID * 2;       // 4 MB
    size_t offH   = offXb + (size_t)N_TOK * DIM * 2;              // 18.9 MB
    size_t offYb  = offH + (size_t)HROWS * HID * 2;               // 8 MB
    size_t offCnt = offYb + (size_t)N_TOK * 2 * OUTD * 2;
    size_t offTl  = offCnt + 256;
    size_t offPkE = offTl + (size_t)NEXP * N_TOK * 4;
    size_t offPkW = offPkE + (size_t)N_TOK * 2 * 4;

    bf16*  W1t    = (bf16*)(ws + offW1t);
    bf16*  W2t    = (bf16*)(ws + offW2t);
    bf16*  xbuf   = (bf16*)(ws + offXb);
    bf16*  hbuf   = (bf16*)(ws + offH);
    bf16*  ybuf   = (bf16*)(ws + offYb);
    int*   cnts   = (int*)(ws + offCnt);
    int*   tlist  = (int*)(ws + offTl);
    int*   pick_e = (int*)(ws + offPkE);
    float* pick_w = (float*)(ws + offPkW);

    prep_gate_kernel<<<8192 + N_TOK / 4, 256, 0, stream>>>(
        W1, W2, Wg, bg, x, W1t, W2t, xbuf, gates_o, topi_o, pick_e, pick_w);

    bucket_kernel<<<NEXP, 256, 0, stream>>>(pick_e, cnts, tlist);

    l1_kernel<<<MT1 * 8, 256, 0, stream>>>(xbuf, W1t, b1, cnts, tlist, hbuf);
    l2_kernel<<<MT1 * 8, 256, 0, stream>>>(hbuf, W2t, cnts, tlist, ybuf);

    combine_kernel<<<N_TOK / 8, 256, 0, stream>>>(ybuf, b2, pick_e, pick_w, out_f);
}

// Round 9
// 81.697 us; speedup vs baseline: 7.8650x; 1.0330x over previous
//
#include <hip/hip_runtime.h>
#include <hip/hip_bf16.h>

#define N_TOK 4096
#define DIM   512
#define HID   1024
#define OUTD  512
#define NEXP  8
#define TOPK  2

#define MT1 72     // max 128-row M-tiles
#define HROWS 9216 // max padded rows

typedef __bf16 bf16;
typedef bf16  bf16x8 __attribute__((ext_vector_type(8)));
typedef bf16  bf16x4 __attribute__((ext_vector_type(4)));
typedef float f32x4  __attribute__((ext_vector_type(4)));

__device__ inline f32x4 mfma16(bf16x8 a, bf16x8 b, f32x4 c) {
    return __builtin_amdgcn_mfma_f32_16x16x32_bf16(a, b, c, 0, 0, 0);
}

__device__ inline void gload16(const bf16* g, char* l) {
    __builtin_amdgcn_global_load_lds(
        (const __attribute__((address_space(1))) void*)g,
        (__attribute__((address_space(3))) void*)l, 16, 0, 0);
}

// decode 128-row m-tile mt -> (expert, row base, list offset, count)
__device__ inline void find_tile(const int* cv, int mt, int& e, int& rb, int& i0, int& ce)
{
    int at = 0, base = 0;
    e = 0; rb = 0; i0 = 0; ce = 0;
#pragma unroll
    for (int ee = 0; ee < NEXP; ++ee) {
        int c = cv[ee]; int n1 = (c + 127) >> 7;
        if (mt >= at && mt < at + n1) {
            e = ee; int lt = mt - at; rb = base + lt * 128; i0 = lt * 128; ce = c;
        }
        at += n1; base += n1 << 7;
    }
}

__device__ inline int tiles_total(const int* cv)
{
    int t = 0;
#pragma unroll
    for (int ee = 0; ee < NEXP; ++ee) t += (cv[ee] + 127) >> 7;
    return t;
}

// bijective XCD-chunked work id (m204): consecutive blockIdx round-robin XCDs,
// so xcd = bid&7, idx = bid>>3; give each XCD a CONTIGUOUS chunk of work ids
// so blocks sharing an A-panel co-locate on one XCD's L2.
__device__ inline int xcd_work_id(int bid, int W)
{
    int xcd = bid & 7, idx = bid >> 3;
    int q = W >> 3, r = W & 7;
    int start = xcd < r ? xcd * (q + 1) : r * (q + 1) + (xcd - r) * q;
    int csz   = xcd < r ? q + 1 : q;
    if (idx >= csz) return -1;
    return start + idx;
}

// ------------- prep (W1/W2 transpose->bf16) + gate, one launch -------------
// blocks [0,4096): W1 [512][1024] -> W1t [1024][512]
// blocks [4096,8192): W2 [1024][512] -> W2t [512][1024]
// blocks [8192,9216): gating (4 tokens per block); WgT built in LDS
__global__ __launch_bounds__(256) void prep_gate_kernel(
    const float* __restrict__ W1, const float* __restrict__ W2,
    const float* __restrict__ Wg, const float* __restrict__ bg,
    const float* __restrict__ x,
    bf16* __restrict__ W1t, bf16* __restrict__ W2t,
    bf16* __restrict__ xb,
    float* __restrict__ gates_out, float* __restrict__ topi_out,
    int* __restrict__ pick_e, float* __restrict__ pick_w)
{
    __shared__ __align__(16) float smem[NEXP * DIM];   // 16 KB (gate) / tile (prep)
    int b = blockIdx.x;

    if (b >= 8192) {
        // ---------------- gate path ----------------
        const float4* Wg4 = (const float4*)Wg;
        for (int i = threadIdx.x; i < DIM * NEXP / 4; i += 256) {
            float4 v = Wg4[i];
#pragma unroll
            for (int j = 0; j < 4; ++j) {
                int idx = i * 4 + j;
                smem[(idx & 7) * DIM + (idx >> 3)] = ((const float*)&v)[j];
            }
        }
        __syncthreads();

        int wave = threadIdx.x >> 6;
        int lane = threadIdx.x & 63;
        int n = (b - 8192) * 4 + wave;

        const float4* x4 = (const float4*)(x + (size_t)n * DIM);
        float4 v0 = x4[lane];
        float4 v1 = x4[lane + 64];

        bf16x4 o0 = { (bf16)v0.x, (bf16)v0.y, (bf16)v0.z, (bf16)v0.w };
        bf16x4 o1 = { (bf16)v1.x, (bf16)v1.y, (bf16)v1.z, (bf16)v1.w };
        bf16x4* xb4 = (bf16x4*)(xb + (size_t)n * DIM);
        xb4[lane]      = o0;
        xb4[lane + 64] = o1;

        float acc[NEXP];
#pragma unroll
        for (int e = 0; e < NEXP; ++e) {
            const float4* wr = (const float4*)(smem + e * DIM);
            float4 w0 = wr[lane];
            float4 w1 = wr[lane + 64];
            acc[e] = v0.x * w0.x + v0.y * w0.y + v0.z * w0.z + v0.w * w0.w
                   + v1.x * w1.x + v1.y * w1.y + v1.z * w1.z + v1.w * w1.w;
        }
#pragma unroll
        for (int off = 32; off >= 1; off >>= 1) {
#pragma unroll
            for (int e = 0; e < NEXP; ++e) acc[e] += __shfl_xor(acc[e], off, 64);
        }
#pragma unroll
        for (int e = 0; e < NEXP; ++e) acc[e] += bg[e];

        float m = acc[0];
#pragma unroll
        for (int e = 1; e < NEXP; ++e) m = fmaxf(m, acc[e]);
        float g[NEXP];
        float s = 0.f;
#pragma unroll
        for (int e = 0; e < NEXP; ++e) { g[e] = expf(acc[e] - m); s += g[e]; }
        float inv_s = 1.f / s;
#pragma unroll
        for (int e = 0; e < NEXP; ++e) g[e] *= inv_s;

        if (lane < NEXP) gates_out[n * NEXP + lane] = g[lane];

        if (lane == 0) {
            int m1 = 0;
#pragma unroll
            for (int e = 1; e < NEXP; ++e) if (g[e] > g[m1]) m1 = e;
            int m2 = (m1 == 0) ? 1 : 0;
#pragma unroll
            for (int e = 0; e < NEXP; ++e) if (e != m1 && g[e] > g[m2]) m2 = e;
            float v1g = g[m1], v2g = g[m2];
            float inv = 1.f / (v1g + v2g);
            topi_out[n * TOPK + 0] = (float)m1;
            topi_out[n * TOPK + 1] = (float)m2;
            int2 pe = { m1, m2 };
            float2 pw = { v1g * inv, v2g * inv };
            *(int2*)(pick_e + n * 2) = pe;
            *(float2*)(pick_w + n * 2) = pw;
        }
        return;
    }

    // ---------------- transpose path ----------------
    float (*tile)[33] = (float(*)[33])smem;   // [32][33]
    const float* src; bf16* dst; int R, C, tilex, rem, e;
    if (b < 4096) {
        e = b >> 9; rem = b & 511; R = DIM; C = HID; tilex = 32;
        src = W1; dst = W1t;
    } else {
        b -= 4096;
        e = b >> 9; rem = b & 511; R = HID; C = OUTD; tilex = 16;
        src = W2; dst = W2t;
    }
    const float* s = src + (size_t)e * R * C;
    bf16* d = dst + (size_t)e * R * C;
    int c0 = (rem % tilex) * 32, r0 = (rem / tilex) * 32;

    int tx = threadIdx.x & 31, ty = threadIdx.x >> 5;
#pragma unroll
    for (int i = 0; i < 4; ++i) {
        int r = ty + i * 8;
        tile[r][tx] = s[(size_t)(r0 + r) * C + c0 + tx];
    }
    __syncthreads();

    int t = threadIdx.x;
    int dc = t >> 3, q = t & 7;
    bf16x4 v;
#pragma unroll
    for (int j = 0; j < 4; ++j) v[j] = (bf16)tile[q * 4 + j][dc];
    *(bf16x4*)(d + (size_t)(c0 + dc) * R + r0 + q * 4) = v;
}

// ------------- bucket: 8 blocks (one per expert); stores pick-index -------------
__global__ __launch_bounds__(256) void bucket_kernel(
    const int* __restrict__ pick_e,
    int* __restrict__ counts, int* __restrict__ tlist)
{
    __shared__ int cnt;
    if (threadIdx.x == 0) cnt = 0;
    __syncthreads();
    int e = blockIdx.x;
    for (int i = threadIdx.x; i < N_TOK * 2; i += 256) {
        if (pick_e[i] == e) {
            int p = atomicAdd(&cnt, 1);
            tlist[e * N_TOK + p] = i;   // pick index: token*2 + slot
        }
    }
    __syncthreads();
    if (threadIdx.x == 0) counts[e] = cnt;
}

// Swizzled K-inner LDS layout (rule #21): slot(row,kc) = row*4 + (kc ^ h(row)),
// h(row) = (row&3) ^ ((row>>2)&1); LDS dest linear, global source inverse-swizzled,
// ds_read applies same XOR -> 2-way bank aliasing (free).

// ------------- layer1: h = relu(X_gather @ W1_e + b1), tile 128x128, K=512 -------------
__global__ __launch_bounds__(256, 4) void l1_kernel(
    const bf16* __restrict__ xb, const bf16* __restrict__ W1t,
    const float* __restrict__ b1, const int* __restrict__ counts,
    const int* __restrict__ tlist, bf16* __restrict__ h)
{
    int cv[NEXP];
#pragma unroll
    for (int e = 0; e < NEXP; ++e) cv[e] = counts[e];
    int wid = xcd_work_id(blockIdx.x, tiles_total(cv) * 8);
    if (wid < 0) return;
    int mt = wid >> 3, nt = wid & 7;
    int e, rb, i0, cnt;
    find_tile(cv, mt, e, rb, i0, cnt);

    __shared__ __align__(16) char lds[32768];  // 2 bufs x (A 8KB + B 8KB)

    int tid = threadIdx.x, w = tid >> 6, l = tid & 63;
    int c0 = w * 128 + l, c1 = c0 + 64;
    int rA0 = c0 >> 2, rA1 = c1 >> 2;
    int kA0 = (c0 & 3) ^ ((rA0 & 3) ^ ((rA0 >> 2) & 1));
    int kA1 = (c1 & 3) ^ ((rA1 & 3) ^ ((rA1 >> 2) & 1));
    int iA0 = i0 + rA0, iA1 = i0 + rA1;
    const int* tl = tlist + e * N_TOK;
    int tok0 = iA0 < cnt ? (tl[iA0] >> 1) : 0;
    int tok1 = iA1 < cnt ? (tl[iA1] >> 1) : 0;
    const bf16* sA0 = xb + (size_t)tok0 * DIM + kA0 * 8;
    const bf16* sA1 = xb + (size_t)tok1 * DIM + kA1 * 8;
    int n0 = nt * 128;
    const bf16* w1e = W1t + (size_t)e * HID * DIM;
    const bf16* sB0 = w1e + (size_t)(n0 + rA0) * DIM + kA0 * 8;
    const bf16* sB1 = w1e + (size_t)(n0 + rA1) * DIM + kA1 * 8;
    int oA0 = c0 * 16, oA1 = c1 * 16;

    f32x4 acc[4][4];
#pragma unroll
    for (int mf = 0; mf < 4; ++mf)
#pragma unroll
        for (int nf = 0; nf < 4; ++nf) acc[mf][nf] = (f32x4){0.f, 0.f, 0.f, 0.f};

    int wm = w >> 1, wn = w & 1;
    int lr = l & 15;
    int kb = ((l >> 4) ^ ((l & 3) ^ ((l >> 2) & 1))) * 16;

    {
        char* A = lds;       char* B = lds + 8192;
        gload16(sA0, A + oA0); gload16(sA1, A + oA1);
        gload16(sB0, B + oA0); gload16(sB1, B + oA1);
    }

    for (int ks = 0; ks < 16; ++ks) {
        __syncthreads();
        if (ks < 15) {
            char* A = lds + (((ks + 1) & 1) * 16384);
            char* B = A + 8192;
            int kof = (ks + 1) * 32;
            gload16(sA0 + kof, A + oA0); gload16(sA1 + kof, A + oA1);
            gload16(sB0 + kof, B + oA0); gload16(sB1 + kof, B + oA1);
        }
        char* A = lds + ((ks & 1) * 16384);
        char* B = A + 8192;
        bf16x8 af[4], bfr[4];
#pragma unroll
        for (int mf = 0; mf < 4; ++mf)
            af[mf] = *(const bf16x8*)(A + (wm * 64 + mf * 16 + lr) * 64 + kb);
#pragma unroll
        for (int nf = 0; nf < 4; ++nf)
            bfr[nf] = *(const bf16x8*)(B + (wn * 64 + nf * 16 + lr) * 64 + kb);
#pragma unroll
        for (int mf = 0; mf < 4; ++mf)
#pragma unroll
            for (int nf = 0; nf < 4; ++nf)
                acc[mf][nf] = mfma16(af[mf], bfr[nf], acc[mf][nf]);
    }

    const float* b1e = b1 + e * HID;
#pragma unroll
    for (int nf = 0; nf < 4; ++nf) {
        int colg = n0 + wn * 64 + nf * 16 + lr;
        float bias = b1e[colg];
#pragma unroll
        for (int mf = 0; mf < 4; ++mf) {
#pragma unroll
            for (int r = 0; r < 4; ++r) {
                int gr = rb + wm * 64 + mf * 16 + (l >> 4) * 4 + r;
                float v = fmaxf(acc[mf][nf][r] + bias, 0.f);
                h[(size_t)gr * HID + colg] = (bf16)v;
            }
        }
    }
}

// ------------- layer2: ybuf[pick] = h @ W2_e, tile 128x128, K=1024 -------------
__global__ __launch_bounds__(256, 4) void l2_kernel(
    const bf16* __restrict__ h, const bf16* __restrict__ W2t,
    const int* __restrict__ counts, const int* __restrict__ tlist,
    bf16* __restrict__ ybuf)
{
    int cv[NEXP];
#pragma unroll
    for (int e = 0; e < NEXP; ++e) cv[e] = counts[e];
    int wid = xcd_work_id(blockIdx.x, tiles_total(cv) * 4);
    if (wid < 0) return;
    int mt = wid >> 2, nt = wid & 3;
    int e, rb, i0, cnt;
    find_tile(cv, mt, e, rb, i0, cnt);

    __shared__ __align__(16) char lds[32768];  // 2 bufs x (A 8KB + B 8KB)

    int tid = threadIdx.x, w = tid >> 6, l = tid & 63;
    int c0 = w * 128 + l, c1 = c0 + 64;
    int rA0 = c0 >> 2, rA1 = c1 >> 2;
    int kA0 = (c0 & 3) ^ ((rA0 & 3) ^ ((rA0 >> 2) & 1));
    int kA1 = (c1 & 3) ^ ((rA1 & 3) ^ ((rA1 >> 2) & 1));
    const bf16* sA0 = h + (size_t)(rb + rA0) * HID + kA0 * 8;
    const bf16* sA1 = h + (size_t)(rb + rA1) * HID + kA1 * 8;
    int n0 = nt * 128;
    const bf16* w2e = W2t + (size_t)e * OUTD * HID;
    const bf16* sB0 = w2e + (size_t)(n0 + rA0) * HID + kA0 * 8;
    const bf16* sB1 = w2e + (size_t)(n0 + rA1) * HID + kA1 * 8;
    int oA0 = c0 * 16, oA1 = c1 * 16;

    f32x4 acc[4][4];
#pragma unroll
    for (int mf = 0; mf < 4; ++mf)
#pragma unroll
        for (int nf = 0; nf < 4; ++nf) acc[mf][nf] = (f32x4){0.f, 0.f, 0.f, 0.f};

    int wm = w >> 1, wn = w & 1;
    int lr = l & 15;
    int kb = ((l >> 4) ^ ((l & 3) ^ ((l >> 2) & 1))) * 16;

    {
        char* A = lds;       char* B = lds + 8192;
        gload16(sA0, A + oA0); gload16(sA1, A + oA1);
        gload16(sB0, B + oA0); gload16(sB1, B + oA1);
    }

    for (int ks = 0; ks < 32; ++ks) {
        __syncthreads();
        if (ks < 31) {
            char* A = lds + (((ks + 1) & 1) * 16384);
            char* B = A + 8192;
            int kof = (ks + 1) * 32;
            gload16(sA0 + kof, A + oA0); gload16(sA1 + kof, A + oA1);
            gload16(sB0 + kof, B + oA0); gload16(sB1 + kof, B + oA1);
        }
        char* A = lds + ((ks & 1) * 16384);
        char* B = A + 8192;
        bf16x8 af[4], bfr[4];
#pragma unroll
        for (int mf = 0; mf < 4; ++mf)
            af[mf] = *(const bf16x8*)(A + (wm * 64 + mf * 16 + lr) * 64 + kb);
#pragma unroll
        for (int nf = 0; nf < 4; ++nf)
            bfr[nf] = *(const bf16x8*)(B + (wn * 64 + nf * 16 + lr) * 64 + kb);
#pragma unroll
        for (int mf = 0; mf < 4; ++mf)
#pragma unroll
            for (int nf = 0; nf < 4; ++nf)
                acc[mf][nf] = mfma16(af[mf], bfr[nf], acc[mf][nf]);
    }

    // epilogue: raw y -> ybuf[pick_index] (bf16); padding rows discarded
    const int* tl = tlist + e * N_TOK;
#pragma unroll
    for (int mf = 0; mf < 4; ++mf) {
#pragma unroll
        for (int r = 0; r < 4; ++r) {
            int rloc = wm * 64 + mf * 16 + (l >> 4) * 4 + r;
            int i = i0 + rloc;
            if (i < cnt) {
                int pi = tl[i];
                bf16* yrow = ybuf + (size_t)pi * OUTD;
#pragma unroll
                for (int nf = 0; nf < 4; ++nf)
                    yrow[n0 + wn * 64 + nf * 16 + lr] = (bf16)acc[mf][nf][r];
            }
        }
    }
}

// ------------- combine: out[n] = w0*(y0+b2[e0]) + w1*(y1+b2[e1]) -------------
__global__ __launch_bounds__(256) void combine_kernel(
    const bf16* __restrict__ ybuf, const float* __restrict__ b2,
    const int* __restrict__ pick_e, const float* __restrict__ pick_w,
    float* __restrict__ out)
{
    int w = threadIdx.x >> 6;
    int l = threadIdx.x & 63;
#pragma unroll
    for (int j = 0; j < 2; ++j) {
        int n = blockIdx.x * 8 + w * 2 + j;
        int e0 = pick_e[n * 2], e1 = pick_e[n * 2 + 1];
        float w0 = pick_w[n * 2], w1 = pick_w[n * 2 + 1];

        const bf16x8* y0 = (const bf16x8*)(ybuf + (size_t)(n * 2) * OUTD);
        const bf16x8* y1 = (const bf16x8*)(ybuf + (size_t)(n * 2 + 1) * OUTD);
        const float4* b20 = (const float4*)(b2 + e0 * OUTD);
        const float4* b21 = (const float4*)(b2 + e1 * OUTD);
        float4* o4 = (float4*)(out + (size_t)n * OUTD);

        bf16x8 a = y0[l];
        bf16x8 b = y1[l];
        float4 c0 = b20[l * 2], c1 = b20[l * 2 + 1];
        float4 d0 = b21[l * 2], d1 = b21[l * 2 + 1];

        float4 r0, r1;
        r0.x = w0 * ((float)a[0] + c0.x) + w1 * ((float)b[0] + d0.x);
        r0.y = w0 * ((float)a[1] + c0.y) + w1 * ((float)b[1] + d0.y);
        r0.z = w0 * ((float)a[2] + c0.z) + w1 * ((float)b[2] + d0.z);
        r0.w = w0 * ((float)a[3] + c0.w) + w1 * ((float)b[3] + d0.w);
        r1.x = w0 * ((float)a[4] + c1.x) + w1 * ((float)b[4] + d1.x);
        r1.y = w0 * ((float)a[5] + c1.y) + w1 * ((float)b[5] + d1.y);
        r1.z = w0 * ((float)a[6] + c1.z) + w1 * ((float)b[6] + d1.z);
        r1.w = w0 * ((float)a[7] + c1.w) + w1 * ((float)b[7] + d1.w);
        o4[l * 2]     = r0;
        o4[l * 2 + 1] = r1;
    }
}

extern "C" void kernel_launch(void* const* d_in, const int* in_sizes, int n_in,
                              void* d_out, int out_size, void* d_ws, size_t ws_size,
                              hipStream_t stream)
{
    const float* x  = (const float*)d_in[0];
    const float* W1 = (const float*)d_in[1];
    const float* b1 = (const float*)d_in[2];
    const float* W2 = (const float*)d_in[3];
    const float* b2 = (const float*)d_in[4];
    const float* Wg = (const float*)d_in[5];
    const float* bg = (const float*)d_in[6];

    float* out_f   = (float*)d_out;
    float* gates_o = out_f + (size_t)N_TOK * OUTD;
    float* topi_o  = gates_o + (size_t)N_TOK * NEXP;

    char* ws = (char*)d_ws;
    size_t offW1t = 0;                                            // 8 MB
    size_t offW2t = offW1t + (size_t)NEXP * HID * DIM * 2;        // 8 MB
    size_t offXb  = offW2t + (size_t)NEXP * OUTD * HID * 2;       // 4 MB
    size_t offH   = offXb + (size_t)N_TOK * DIM * 2;              // 18.9 MB
    size_t offYb  = offH + (size_t)HROWS * HID * 2;               // 8 MB
    size_t offCnt = offYb + (size_t)N_TOK * 2 * OUTD * 2;
    size_t offTl  = offCnt + 256;
    size_t offPkE = offTl + (size_t)NEXP * N_TOK * 4;
    size_t offPkW = offPkE + (size_t)N_TOK * 2 * 4;

    bf16*  W1t    = (bf16*)(ws + offW1t);
    bf16*  W2t    = (bf16*)(ws + offW2t);
    bf16*  xbuf   = (bf16*)(ws + offXb);
    bf16*  hbuf   = (bf16*)(ws + offH);
    bf16*  ybuf   = (bf16*)(ws + offYb);
    int*   cnts   = (int*)(ws + offCnt);
    int*   tlist  = (int*)(ws + offTl);
    int*   pick_e = (int*)(ws + offPkE);
    float* pick_w = (float*)(ws + offPkW);

    prep_gate_kernel<<<8192 + N_TOK / 4, 256, 0, stream>>>(
        W1, W2, Wg, bg, x, W1t, W2t, xbuf, gates_o, topi_o, pick_e, pick_w);

    bucket_kernel<<<NEXP, 256, 0, stream>>>(pick_e, cnts, tlist);

    l1_kernel<<<MT1 * 8, 256, 0, stream>>>(xbuf, W1t, b1, cnts, tlist, hbuf);
    l2_kernel<<<MT1 * 4, 256, 0, stream>>>(hbuf, W2t, cnts, tlist, ybuf);

    combine_kernel<<<N_TOK / 8, 256, 0, stream>>>(ybuf, b2, pick_e, pick_w, out_f);
}

// Round 10
// 77.185 us; speedup vs baseline: 8.3248x; 1.0585x over previous
//
#include <hip/hip_runtime.h>
#include <hip/hip_bf16.h>

#define N_TOK 4096
#define DIM   512
#define HID   1024
#define OUTD  512
#define NEXP  8
#define TOPK  2

#define MT1 72     // max 128-row M-tiles
#define HROWS 9216 // max padded rows

typedef __bf16 bf16;
typedef bf16  bf16x8 __attribute__((ext_vector_type(8)));
typedef bf16  bf16x4 __attribute__((ext_vector_type(4)));
typedef float f32x4  __attribute__((ext_vector_type(4)));

__device__ inline f32x4 mfma16(bf16x8 a, bf16x8 b, f32x4 c) {
    return __builtin_amdgcn_mfma_f32_16x16x32_bf16(a, b, c, 0, 0, 0);
}

__device__ inline void gload16(const bf16* g, char* l) {
    __builtin_amdgcn_global_load_lds(
        (const __attribute__((address_space(1))) void*)g,
        (__attribute__((address_space(3))) void*)l, 16, 0, 0);
}

// ------------- prep (W1/W2 transpose->bf16) + gate, one launch -------------
// blocks [0,4096): W1 [512][1024] -> W1t [1024][512]
// blocks [4096,8192): W2 [1024][512] -> W2t [512][1024]
// blocks [8192,9216): gating (4 tokens per block); WgT built in LDS
__global__ __launch_bounds__(256) void prep_gate_kernel(
    const float* __restrict__ W1, const float* __restrict__ W2,
    const float* __restrict__ Wg, const float* __restrict__ bg,
    const float* __restrict__ x,
    bf16* __restrict__ W1t, bf16* __restrict__ W2t,
    bf16* __restrict__ xb,
    float* __restrict__ gates_out, float* __restrict__ topi_out,
    int* __restrict__ pick_e, float* __restrict__ pick_w)
{
    __shared__ __align__(16) float smem[NEXP * DIM];   // 16 KB (gate) / tile (prep)
    int b = blockIdx.x;

    if (b >= 8192) {
        // ---------------- gate path ----------------
        const float4* Wg4 = (const float4*)Wg;
        for (int i = threadIdx.x; i < DIM * NEXP / 4; i += 256) {
            float4 v = Wg4[i];
#pragma unroll
            for (int j = 0; j < 4; ++j) {
                int idx = i * 4 + j;
                smem[(idx & 7) * DIM + (idx >> 3)] = ((const float*)&v)[j];
            }
        }
        __syncthreads();

        int wave = threadIdx.x >> 6;
        int lane = threadIdx.x & 63;
        int n = (b - 8192) * 4 + wave;

        const float4* x4 = (const float4*)(x + (size_t)n * DIM);
        float4 v0 = x4[lane];
        float4 v1 = x4[lane + 64];

        bf16x4 o0 = { (bf16)v0.x, (bf16)v0.y, (bf16)v0.z, (bf16)v0.w };
        bf16x4 o1 = { (bf16)v1.x, (bf16)v1.y, (bf16)v1.z, (bf16)v1.w };
        bf16x4* xb4 = (bf16x4*)(xb + (size_t)n * DIM);
        xb4[lane]      = o0;
        xb4[lane + 64] = o1;

        float acc[NEXP];
#pragma unroll
        for (int e = 0; e < NEXP; ++e) {
            const float4* wr = (const float4*)(smem + e * DIM);
            float4 w0 = wr[lane];
            float4 w1 = wr[lane + 64];
            acc[e] = v0.x * w0.x + v0.y * w0.y + v0.z * w0.z + v0.w * w0.w
                   + v1.x * w1.x + v1.y * w1.y + v1.z * w1.z + v1.w * w1.w;
        }
#pragma unroll
        for (int off = 32; off >= 1; off >>= 1) {
#pragma unroll
            for (int e = 0; e < NEXP; ++e) acc[e] += __shfl_xor(acc[e], off, 64);
        }
#pragma unroll
        for (int e = 0; e < NEXP; ++e) acc[e] += bg[e];

        float m = acc[0];
#pragma unroll
        for (int e = 1; e < NEXP; ++e) m = fmaxf(m, acc[e]);
        float g[NEXP];
        float s = 0.f;
#pragma unroll
        for (int e = 0; e < NEXP; ++e) { g[e] = expf(acc[e] - m); s += g[e]; }
        float inv_s = 1.f / s;
#pragma unroll
        for (int e = 0; e < NEXP; ++e) g[e] *= inv_s;

        if (lane < NEXP) gates_out[n * NEXP + lane] = g[lane];

        if (lane == 0) {
            int m1 = 0;
#pragma unroll
            for (int e = 1; e < NEXP; ++e) if (g[e] > g[m1]) m1 = e;
            int m2 = (m1 == 0) ? 1 : 0;
#pragma unroll
            for (int e = 0; e < NEXP; ++e) if (e != m1 && g[e] > g[m2]) m2 = e;
            float v1g = g[m1], v2g = g[m2];
            float inv = 1.f / (v1g + v2g);
            topi_out[n * TOPK + 0] = (float)m1;
            topi_out[n * TOPK + 1] = (float)m2;
            int2 pe = { m1, m2 };
            float2 pw = { v1g * inv, v2g * inv };
            *(int2*)(pick_e + n * 2) = pe;
            *(float2*)(pick_w + n * 2) = pw;
        }
        return;
    }

    // ---------------- transpose path ----------------
    float (*tile)[33] = (float(*)[33])smem;   // [32][33]
    const float* src; bf16* dst; int R, C, tilex, rem, e;
    if (b < 4096) {
        e = b >> 9; rem = b & 511; R = DIM; C = HID; tilex = 32;
        src = W1; dst = W1t;
    } else {
        b -= 4096;
        e = b >> 9; rem = b & 511; R = HID; C = OUTD; tilex = 16;
        src = W2; dst = W2t;
    }
    const float* s = src + (size_t)e * R * C;
    bf16* d = dst + (size_t)e * R * C;
    int c0 = (rem % tilex) * 32, r0 = (rem / tilex) * 32;

    int tx = threadIdx.x & 31, ty = threadIdx.x >> 5;
#pragma unroll
    for (int i = 0; i < 4; ++i) {
        int r = ty + i * 8;
        tile[r][tx] = s[(size_t)(r0 + r) * C + c0 + tx];
    }
    __syncthreads();

    int t = threadIdx.x;
    int dc = t >> 3, q = t & 7;
    bf16x4 v;
#pragma unroll
    for (int j = 0; j < 4; ++j) v[j] = (bf16)tile[q * 4 + j][dc];
    *(bf16x4*)(d + (size_t)(c0 + dc) * R + r0 + q * 4) = v;
}

// ------------- bucket + tile scheduler: one block, 1024 threads -------------
__global__ __launch_bounds__(1024) void bucket_sched_kernel(
    const int* __restrict__ pick_e,
    int* __restrict__ counts, int* __restrict__ tlist, int* __restrict__ meta)
{
    __shared__ int cnt[NEXP];
    if (threadIdx.x < NEXP) cnt[threadIdx.x] = 0;
    __syncthreads();
    for (int i = threadIdx.x; i < N_TOK * 2; i += 1024) {
        int e = pick_e[i];
        int p = atomicAdd(&cnt[e], 1);
        tlist[e * N_TOK + p] = i;   // pick index: token*2 + slot
    }
    __syncthreads();
    if (threadIdx.x == 0) {
        int base = 0, t1 = 0;
        for (int e = 0; e < NEXP; ++e) {
            int c = cnt[e];
            counts[e] = c;
            int n1 = (c + 127) >> 7;
            for (int lt = 0; lt < n1; ++lt) {
                meta[2 + t1 * 3]     = e;
                meta[2 + t1 * 3 + 1] = base + lt * 128;
                meta[2 + t1 * 3 + 2] = lt * 128;
                ++t1;
            }
            base += n1 << 7;
        }
        meta[0] = t1;
    }
}

// Swizzled K-inner LDS layout (rule #21): slot(row,kc) = row*4 + (kc ^ h(row)),
// h(row) = (row&3) ^ ((row>>2)&1); LDS dest linear, global source inverse-swizzled,
// ds_read applies same XOR -> 2-way bank aliasing (free).
// Epilogue: C restaged via LDS with 16B-granule XOR swizzle g = ch ^ (row&3) so
// the 4 row-groups of a wave ds_write land on disjoint bank sets; global writes
// become 16 consecutive lanes covering one full 256B row (bf16x8 each).

// ------------- layer1: h = relu(X_gather @ W1_e + b1), tile 128x128, K=512 -------------
__global__ __launch_bounds__(256, 4) void l1_kernel(
    const bf16* __restrict__ xb, const bf16* __restrict__ W1t,
    const float* __restrict__ b1, const int* __restrict__ counts,
    const int* __restrict__ tlist, const int* __restrict__ meta,
    bf16* __restrict__ h)
{
    int mt = blockIdx.x >> 3, nt = blockIdx.x & 7;
    if (mt >= meta[0]) return;
    const int* s1 = meta + 2 + mt * 3;
    int e = s1[0], rb = s1[1], i0 = s1[2];
    int cnt = counts[e];

    __shared__ __align__(16) char lds[32768];  // 2 bufs x (A 8KB + B 8KB)

    int tid = threadIdx.x, w = tid >> 6, l = tid & 63;
    int c0 = w * 128 + l, c1 = c0 + 64;
    int rA0 = c0 >> 2, rA1 = c1 >> 2;
    int kA0 = (c0 & 3) ^ ((rA0 & 3) ^ ((rA0 >> 2) & 1));
    int kA1 = (c1 & 3) ^ ((rA1 & 3) ^ ((rA1 >> 2) & 1));
    int iA0 = i0 + rA0, iA1 = i0 + rA1;
    const int* tl = tlist + e * N_TOK;
    int tok0 = iA0 < cnt ? (tl[iA0] >> 1) : 0;
    int tok1 = iA1 < cnt ? (tl[iA1] >> 1) : 0;
    const bf16* sA0 = xb + (size_t)tok0 * DIM + kA0 * 8;
    const bf16* sA1 = xb + (size_t)tok1 * DIM + kA1 * 8;
    int n0 = nt * 128;
    const bf16* w1e = W1t + (size_t)e * HID * DIM;
    const bf16* sB0 = w1e + (size_t)(n0 + rA0) * DIM + kA0 * 8;
    const bf16* sB1 = w1e + (size_t)(n0 + rA1) * DIM + kA1 * 8;
    int oA0 = c0 * 16, oA1 = c1 * 16;

    f32x4 acc[4][4];
#pragma unroll
    for (int mf = 0; mf < 4; ++mf)
#pragma unroll
        for (int nf = 0; nf < 4; ++nf) acc[mf][nf] = (f32x4){0.f, 0.f, 0.f, 0.f};

    int wm = w >> 1, wn = w & 1;
    int lr = l & 15;
    int kb = ((l >> 4) ^ ((l & 3) ^ ((l >> 2) & 1))) * 16;

    {
        char* A = lds;       char* B = lds + 8192;
        gload16(sA0, A + oA0); gload16(sA1, A + oA1);
        gload16(sB0, B + oA0); gload16(sB1, B + oA1);
    }

    for (int ks = 0; ks < 16; ++ks) {
        __syncthreads();
        if (ks < 15) {
            char* A = lds + (((ks + 1) & 1) * 16384);
            char* B = A + 8192;
            int kof = (ks + 1) * 32;
            gload16(sA0 + kof, A + oA0); gload16(sA1 + kof, A + oA1);
            gload16(sB0 + kof, B + oA0); gload16(sB1 + kof, B + oA1);
        }
        char* A = lds + ((ks & 1) * 16384);
        char* B = A + 8192;
        bf16x8 af[4], bfr[4];
#pragma unroll
        for (int mf = 0; mf < 4; ++mf)
            af[mf] = *(const bf16x8*)(A + (wm * 64 + mf * 16 + lr) * 64 + kb);
#pragma unroll
        for (int nf = 0; nf < 4; ++nf)
            bfr[nf] = *(const bf16x8*)(B + (wn * 64 + nf * 16 + lr) * 64 + kb);
#pragma unroll
        for (int mf = 0; mf < 4; ++mf)
#pragma unroll
            for (int nf = 0; nf < 4; ++nf)
                acc[mf][nf] = mfma16(af[mf], bfr[nf], acc[mf][nf]);
    }

    // epilogue: bias+relu, restage C through LDS, coalesced bf16x8 row stores
    __syncthreads();
    bf16* ct = (bf16*)lds;
    const float* b1e = b1 + e * HID;
#pragma unroll
    for (int nf = 0; nf < 4; ++nf) {
        int col = wn * 64 + nf * 16 + lr;
        float bias = b1e[n0 + col];
#pragma unroll
        for (int mf = 0; mf < 4; ++mf) {
#pragma unroll
            for (int r = 0; r < 4; ++r) {
                int row = wm * 64 + mf * 16 + (l >> 4) * 4 + r;
                float v = fmaxf(acc[mf][nf][r] + bias, 0.f);
                int g = (col >> 3) ^ (row & 3);
                ct[row * 128 + g * 8 + (col & 7)] = (bf16)v;
            }
        }
    }
    __syncthreads();
#pragma unroll
    for (int p = 0; p < 8; ++p) {
        int row = p * 16 + (tid >> 4);
        int ch = tid & 15;
        int g = ch ^ (row & 3);
        bf16x8 v = *(const bf16x8*)(ct + row * 128 + g * 8);
        *(bf16x8*)(h + (size_t)(rb + row) * HID + n0 + ch * 8) = v;
    }
}

// ------------- layer2: ybuf[pick] = h @ W2_e, tile 128x128, K=1024 -------------
__global__ __launch_bounds__(256, 4) void l2_kernel(
    const bf16* __restrict__ h, const bf16* __restrict__ W2t,
    const int* __restrict__ counts, const int* __restrict__ tlist,
    const int* __restrict__ meta, bf16* __restrict__ ybuf)
{
    int mt = blockIdx.x >> 2, nt = blockIdx.x & 3;
    if (mt >= meta[0]) return;
    const int* s1 = meta + 2 + mt * 3;
    int e = s1[0], rb = s1[1], i0 = s1[2];
    int cnt = counts[e];

    __shared__ __align__(16) char lds[32768];  // 2 bufs x (A 8KB + B 8KB)

    int tid = threadIdx.x, w = tid >> 6, l = tid & 63;
    int c0 = w * 128 + l, c1 = c0 + 64;
    int rA0 = c0 >> 2, rA1 = c1 >> 2;
    int kA0 = (c0 & 3) ^ ((rA0 & 3) ^ ((rA0 >> 2) & 1));
    int kA1 = (c1 & 3) ^ ((rA1 & 3) ^ ((rA1 >> 2) & 1));
    const bf16* sA0 = h + (size_t)(rb + rA0) * HID + kA0 * 8;
    const bf16* sA1 = h + (size_t)(rb + rA1) * HID + kA1 * 8;
    int n0 = nt * 128;
    const bf16* w2e = W2t + (size_t)e * OUTD * HID;
    const bf16* sB0 = w2e + (size_t)(n0 + rA0) * HID + kA0 * 8;
    const bf16* sB1 = w2e + (size_t)(n0 + rA1) * HID + kA1 * 8;
    int oA0 = c0 * 16, oA1 = c1 * 16;

    f32x4 acc[4][4];
#pragma unroll
    for (int mf = 0; mf < 4; ++mf)
#pragma unroll
        for (int nf = 0; nf < 4; ++nf) acc[mf][nf] = (f32x4){0.f, 0.f, 0.f, 0.f};

    int wm = w >> 1, wn = w & 1;
    int lr = l & 15;
    int kb = ((l >> 4) ^ ((l & 3) ^ ((l >> 2) & 1))) * 16;

    {
        char* A = lds;       char* B = lds + 8192;
        gload16(sA0, A + oA0); gload16(sA1, A + oA1);
        gload16(sB0, B + oA0); gload16(sB1, B + oA1);
    }

    for (int ks = 0; ks < 32; ++ks) {
        __syncthreads();
        if (ks < 31) {
            char* A = lds + (((ks + 1) & 1) * 16384);
            char* B = A + 8192;
            int kof = (ks + 1) * 32;
            gload16(sA0 + kof, A + oA0); gload16(sA1 + kof, A + oA1);
            gload16(sB0 + kof, B + oA0); gload16(sB1 + kof, B + oA1);
        }
        char* A = lds + ((ks & 1) * 16384);
        char* B = A + 8192;
        bf16x8 af[4], bfr[4];
#pragma unroll
        for (int mf = 0; mf < 4; ++mf)
            af[mf] = *(const bf16x8*)(A + (wm * 64 + mf * 16 + lr) * 64 + kb);
#pragma unroll
        for (int nf = 0; nf < 4; ++nf)
            bfr[nf] = *(const bf16x8*)(B + (wn * 64 + nf * 16 + lr) * 64 + kb);
#pragma unroll
        for (int mf = 0; mf < 4; ++mf)
#pragma unroll
            for (int nf = 0; nf < 4; ++nf)
                acc[mf][nf] = mfma16(af[mf], bfr[nf], acc[mf][nf]);
    }

    // epilogue: restage raw y through LDS, coalesced bf16x8 row stores to ybuf[pick]
    __syncthreads();
    bf16* ct = (bf16*)lds;
#pragma unroll
    for (int nf = 0; nf < 4; ++nf) {
        int col = wn * 64 + nf * 16 + lr;
#pragma unroll
        for (int mf = 0; mf < 4; ++mf) {
#pragma unroll
            for (int r = 0; r < 4; ++r) {
                int row = wm * 64 + mf * 16 + (l >> 4) * 4 + r;
                int g = (col >> 3) ^ (row & 3);
                ct[row * 128 + g * 8 + (col & 7)] = (bf16)acc[mf][nf][r];
            }
        }
    }
    __syncthreads();
    const int* tl = tlist + e * N_TOK;
#pragma unroll
    for (int p = 0; p < 8; ++p) {
        int row = p * 16 + (tid >> 4);
        int i = i0 + row;
        if (i < cnt) {
            int pi = tl[i];
            int ch = tid & 15;
            int g = ch ^ (row & 3);
            bf16x8 v = *(const bf16x8*)(ct + row * 128 + g * 8);
            *(bf16x8*)(ybuf + (size_t)pi * OUTD + n0 + ch * 8) = v;
        }
    }
}

// ------------- combine: out[n] = w0*(y0+b2[e0]) + w1*(y1+b2[e1]) -------------
__global__ __launch_bounds__(256) void combine_kernel(
    const bf16* __restrict__ ybuf, const float* __restrict__ b2,
    const int* __restrict__ pick_e, const float* __restrict__ pick_w,
    float* __restrict__ out)
{
    int wave = threadIdx.x >> 6;
    int lane = threadIdx.x & 63;
    int n = blockIdx.x * 4 + wave;

    int e0 = pick_e[n * 2], e1 = pick_e[n * 2 + 1];
    float w0 = pick_w[n * 2], w1 = pick_w[n * 2 + 1];

    const bf16x8* y0 = (const bf16x8*)(ybuf + (size_t)(n * 2) * OUTD);
    const bf16x8* y1 = (const bf16x8*)(ybuf + (size_t)(n * 2 + 1) * OUTD);
    const float4* b20 = (const float4*)(b2 + e0 * OUTD);
    const float4* b21 = (const float4*)(b2 + e1 * OUTD);
    float4* o4 = (float4*)(out + (size_t)n * OUTD);

    bf16x8 a = y0[lane];
    bf16x8 b = y1[lane];
    float4 c0 = b20[lane * 2], c1 = b20[lane * 2 + 1];
    float4 d0 = b21[lane * 2], d1 = b21[lane * 2 + 1];

    float4 r0, r1;
    r0.x = w0 * ((float)a[0] + c0.x) + w1 * ((float)b[0] + d0.x);
    r0.y = w0 * ((float)a[1] + c0.y) + w1 * ((float)b[1] + d0.y);
    r0.z = w0 * ((float)a[2] + c0.z) + w1 * ((float)b[2] + d0.z);
    r0.w = w0 * ((float)a[3] + c0.w) + w1 * ((float)b[3] + d0.w);
    r1.x = w0 * ((float)a[4] + c1.x) + w1 * ((float)b[4] + d1.x);
    r1.y = w0 * ((float)a[5] + c1.y) + w1 * ((float)b[5] + d1.y);
    r1.z = w0 * ((float)a[6] + c1.z) + w1 * ((float)b[6] + d1.z);
    r1.w = w0 * ((float)a[7] + c1.w) + w1 * ((float)b[7] + d1.w);
    o4[lane * 2]     = r0;
    o4[lane * 2 + 1] = r1;
}

extern "C" void kernel_launch(void* const* d_in, const int* in_sizes, int n_in,
                              void* d_out, int out_size, void* d_ws, size_t ws_size,
                              hipStream_t stream)
{
    const float* x  = (const float*)d_in[0];
    const float* W1 = (const float*)d_in[1];
    const float* b1 = (const float*)d_in[2];
    const float* W2 = (const float*)d_in[3];
    const float* b2 = (const float*)d_in[4];
    const float* Wg = (const float*)d_in[5];
    const float* bg = (const float*)d_in[6];

    float* out_f   = (float*)d_out;
    float* gates_o = out_f + (size_t)N_TOK * OUTD;
    float* topi_o  = gates_o + (size_t)N_TOK * NEXP;

    char* ws = (char*)d_ws;
    size_t offW1t = 0;                                            // 8 MB
    size_t offW2t = offW1t + (size_t)NEXP * HID * DIM * 2;        // 8 MB
    size_t offXb  = offW2t + (size_t)NEXP * OUTD * HID * 2;       // 4 MB
    size_t offH   = offXb + (size_t)N_TOK * DIM * 2;              // 18.9 MB
    size_t offYb  = offH + (size_t)HROWS * HID * 2;               // 8 MB
    size_t offCnt = offYb + (size_t)N_TOK * 2 * OUTD * 2;
    size_t offTl  = offCnt + 256;
    size_t offMeta = offTl + (size_t)NEXP * N_TOK * 4;
    size_t offPkE = offMeta + 4096;
    size_t offPkW = offPkE + (size_t)N_TOK * 2 * 4;

    bf16*  W1t    = (bf16*)(ws + offW1t);
    bf16*  W2t    = (bf16*)(ws + offW2t);
    bf16*  xbuf   = (bf16*)(ws + offXb);
    bf16*  hbuf   = (bf16*)(ws + offH);
    bf16*  ybuf   = (bf16*)(ws + offYb);
    int*   cnts   = (int*)(ws + offCnt);
    int*   tlist  = (int*)(ws + offTl);
    int*   meta   = (int*)(ws + offMeta);
    int*   pick_e = (int*)(ws + offPkE);
    float* pick_w = (float*)(ws + offPkW);

    prep_gate_kernel<<<8192 + N_TOK / 4, 256, 0, stream>>>(
        W1, W2, Wg, bg, x, W1t, W2t, xbuf, gates_o, topi_o, pick_e, pick_w);

    bucket_sched_kernel<<<1, 1024, 0, stream>>>(pick_e, cnts, tlist, meta);

    l1_kernel<<<MT1 * 8, 256, 0, stream>>>(xbuf, W1t, b1, cnts, tlist, meta, hbuf);
    l2_kernel<<<MT1 * 4, 256, 0, stream>>>(hbuf, W2t, cnts, tlist, meta, ybuf);

    combine_kernel<<<N_TOK / 4, 256, 0, stream>>>(ybuf, b2, pick_e, pick_w, out_f);
}